// Round 4
// baseline (641.484 us; speedup 1.0000x reference)
//
#include <hip/hip_runtime.h>

typedef __attribute__((ext_vector_type(8))) short bf16x8;
typedef __attribute__((ext_vector_type(4))) short short4v;
typedef __attribute__((ext_vector_type(4))) float f32x4;

#define CP 36   // shorts per t-row (32c + 4 pad): 72B rows -> conflict-free b64 r/w
#define TL 130  // 128 t + 2 halo columns

__device__ __forceinline__ unsigned short f2bf(float v) {
    unsigned u = __builtin_bit_cast(unsigned, v);
    return (unsigned short)((u + 0x7fffu + ((u >> 16) & 1u)) >> 16);
}

__device__ __forceinline__ float dampf(float tt) {
    return (1.0f - 0.1f * fabsf(tt - 128.f) * (1.f / 128.f))
         * (1.0f - 0.1f * fabsf(tt - 64.f) * (1.f / 64.f));
}

// ---- W reorder: [o][c][kh][kw] f32 -> [k9][o][c] bf16 ----
__global__ __launch_bounds__(256) void prep_w(const float* __restrict__ W,
                                              unsigned short* __restrict__ Wr) {
    int id = blockIdx.x * 256 + threadIdx.x;
    if (id >= 9 * 128 * 64) return;
    int c = id & 63, o = (id >> 6) & 127, k9 = id >> 13;
    Wr[id] = f2bf(W[(o * 64 + c) * 9 + k9]);
}

// ---- main conv: block=(n,f,t-half), 4 waves, out tile 128o x 128t ----
__global__ __launch_bounds__(256, 4) void damp_conv_mfma(
    const float* __restrict__ x, const unsigned short* __restrict__ Wr,
    const float* __restrict__ b, float* __restrict__ out)
{
    __shared__ unsigned short xs[3 * TL * CP];  // 28,080 B -> 4 blocks/CU

    const int tid  = threadIdx.x;
    const int lane = tid & 63;
    const int wid  = tid >> 6;       // 0..3
    const int q    = lane & 3;
    const int p16  = lane >> 2;

    const int raw = blockIdx.x;
    const int logical = (raw & 7) * 1024 + (raw >> 3);  // XCD-chunked, bijective (8192%8==0)
    const int n  = logical >> 8;
    const int f  = (logical >> 1) & 127;
    const int th = logical & 1;
    const int tbase = th * 128;

    const int lo16 = lane & 15;
    const int hi2  = lane >> 4;
    const int m0 = (wid >> 1) * 64;  // wave o-base
    const int n0 = (wid & 1) * 64;   // wave t-base (local)

    const unsigned selv = (q & 1) ? 0x07060302u : 0x05040100u;

    float dmp[2][4];
    #pragma unroll
    for (int s = 0; s < 2; ++s)
        #pragma unroll
        for (int j = 0; j < 4; ++j)
            dmp[s][j] = dampf((float)(tbase + 64 * s + 4 * p16 + j));

    f32x4 acc[4][4];
    #pragma unroll
    for (int i = 0; i < 4; ++i)
        #pragma unroll
        for (int j = 0; j < 4; ++j) acc[i][j] = (f32x4){0.f, 0.f, 0.f, 0.f};

    // ---- staging: 12 float4 per thread per 32c chunk ----
    auto issue_main = [&](int cc, float4* buf) {
        #pragma unroll
        for (int j = 0; j < 12; ++j) {
            int idx = wid * 12 + j;
            int f2 = idx >> 4, rem = idx & 15;
            int c0 = (rem >> 1) * 4, s = rem & 1;
            int fg = f + f2 - 1;
            bool fok = (unsigned)fg < 128u;
            const float* src = x + (((size_t)(n * 64 + cc + c0 + q)) * 128 + (fok ? fg : 0)) * 256
                             + tbase + 64 * s + 4 * p16;
            buf[j] = fok ? *(const float4*)src : (float4){0.f, 0.f, 0.f, 0.f};
        }
    };

    // interior halo column (one real t neighbor) : 96 threads, 1 float each
    auto issue_halo = [&](int cc, float& hv) {
        hv = 0.f;
        if (tid < 96) {
            int c = tid & 31, f2 = tid >> 5;
            int fg = f + f2 - 1;
            if ((unsigned)fg < 128u) {
                int t_h = th ? 127 : 128;  // global t of the real halo
                hv = x[(((size_t)(n * 64 + cc + c)) * 128 + fg) * 256 + t_h];
            }
        }
    };

    auto write_halo = [&](float hv) {
        if (tid < 96) {
            int c = tid & 31, f2 = tid >> 5;
            float dh = dampf(th ? 127.f : 128.f);
            xs[(f2 * TL + (th ? 0 : TL - 1)) * CP + c] = f2bf(hv * dh);  // real side
            xs[(f2 * TL + (th ? TL - 1 : 0)) * CP + c] = 0;              // pad side
        }
    };

    auto write_main = [&](const float4* buf) {
        #pragma unroll
        for (int j = 0; j < 12; ++j) {
            int idx = wid * 12 + j;
            int f2 = idx >> 4, rem = idx & 15;
            int c0 = (rem >> 1) * 4, s = rem & 1;
            float4 v = buf[j];
            unsigned d0 = (unsigned)f2bf(v.x * dmp[s][0]) | ((unsigned)f2bf(v.y * dmp[s][1]) << 16);
            unsigned d1 = (unsigned)f2bf(v.z * dmp[s][2]) | ((unsigned)f2bf(v.w * dmp[s][3]) << 16);
            // 4x4 u16 quad transpose -> lane owns 4 consecutive c at t_loc = 64s + lane
            unsigned p0 = __shfl_xor((int)d0, 2);
            unsigned p1 = __shfl_xor((int)d1, 2);
            bool hi = (lane >> 1) & 1;
            unsigned own = hi ? d1 : d0;
            unsigned oth = hi ? p1 : p0;
            unsigned sown = __shfl_xor((int)own, 1);
            unsigned soth = __shfl_xor((int)oth, 1);
            bool b0 = q & 1, b1 = q & 2;
            unsigned a0 = b0 ? sown : own, a1 = b0 ? own : sown;
            unsigned g0 = b0 ? soth : oth, g1 = b0 ? oth : soth;
            unsigned e0 = b1 ? g0 : a0, e1 = b1 ? g1 : a1;
            unsigned e2 = b1 ? a0 : g0, e3 = b1 ? a1 : g1;
            unsigned r0 = __builtin_amdgcn_perm(e1, e0, selv);
            unsigned r1 = __builtin_amdgcn_perm(e3, e2, selv);
            unsigned* dst = (unsigned*)&xs[((f2 * TL + 1 + 64 * s + lane) * CP + c0)];
            dst[0] = r0;
            dst[1] = r1;
        }
    };

    auto mfma_chunk = [&](int cc) {
        #pragma unroll
        for (int kh = 0; kh < 3; ++kh) {
            #pragma unroll
            for (int kw = 0; kw < 3; ++kw) {
                bf16x8 af[4];
                #pragma unroll
                for (int fm = 0; fm < 4; ++fm) {
                    int o = m0 + fm * 16 + lo16;
                    af[fm] = *(const bf16x8*)(Wr + (((kh * 3 + kw) * 128 + o) * 64 + cc + hi2 * 8));
                }
                #pragma unroll
                for (int fn = 0; fn < 4; ++fn) {
                    int row = n0 + fn * 16 + lo16 + kw;
                    const unsigned short* pb = &xs[(kh * TL + row) * CP + hi2 * 8];
                    short4v blo = *(const short4v*)pb;
                    short4v bhi = *(const short4v*)(pb + 4);
                    bf16x8 bx = {blo.x, blo.y, blo.z, blo.w, bhi.x, bhi.y, bhi.z, bhi.w};
                    __builtin_amdgcn_s_setprio(1);
                    #pragma unroll
                    for (int fm = 0; fm < 4; ++fm)
                        acc[fm][fn] = __builtin_amdgcn_mfma_f32_16x16x32_bf16(
                            af[fm], bx, acc[fm][fn], 0, 0, 0);
                    __builtin_amdgcn_s_setprio(0);
                }
            }
        }
    };

    float4 buf0[12];
    float h0, h1;
    issue_halo(0, h0);
    issue_main(0, buf0);
    write_main(buf0);
    write_halo(h0);
    __syncthreads();

    float4 buf1[12];
    issue_main(32, buf1);   // prefetch chunk 1 under chunk-0 MFMA
    issue_halo(32, h1);
    mfma_chunk(0);
    __syncthreads();

    write_main(buf1);
    write_halo(h1);
    __syncthreads();
    mfma_chunk(32);

    // ---- epilogue ----
    #pragma unroll
    for (int fm = 0; fm < 4; ++fm) {
        int obase = m0 + fm * 16 + hi2 * 4;
        #pragma unroll
        for (int r = 0; r < 4; ++r) {
            int o = obase + r;
            float bias = b[o];
            #pragma unroll
            for (int fn = 0; fn < 4; ++fn) {
                int t = tbase + n0 + fn * 16 + lo16;
                out[(((size_t)n * 128 + o) * 128 + f) * 256 + t] = acc[fm][fn][r] + bias;
            }
        }
    }
}

extern "C" void kernel_launch(void* const* d_in, const int* in_sizes, int n_in,
                              void* d_out, int out_size, void* d_ws, size_t ws_size,
                              hipStream_t stream) {
    const float* x = (const float*)d_in[0];
    const float* W = (const float*)d_in[1];
    const float* b = (const float*)d_in[2];
    float* out = (float*)d_out;
    unsigned short* Wr = (unsigned short*)d_ws;  // 147,456 B

    hipLaunchKernelGGL(prep_w, dim3(288), dim3(256), 0, stream, W, Wr);
    hipLaunchKernelGGL(damp_conv_mfma, dim3(8192), dim3(256), 0, stream, x, Wr, b, out);
}

// Round 5
// 460.384 us; speedup vs baseline: 1.3934x; 1.3934x over previous
//
#include <hip/hip_runtime.h>

typedef __attribute__((ext_vector_type(8))) short bf16x8;
typedef __attribute__((ext_vector_type(4))) short short4v;
typedef __attribute__((ext_vector_type(4))) float f32x4;

#define CP 36   // shorts per t-row (32c + 4 pad): 72B rows -> conflict-free b64 r/w
#define TL 130  // 128 t + 2 halo columns

__device__ __forceinline__ unsigned short f2bf(float v) {
    unsigned u = __builtin_bit_cast(unsigned, v);
    return (unsigned short)((u + 0x7fffu + ((u >> 16) & 1u)) >> 16);
}

__device__ __forceinline__ float dampf(float tt) {
    return (1.0f - 0.1f * fabsf(tt - 128.f) * (1.f / 128.f))
         * (1.0f - 0.1f * fabsf(tt - 64.f) * (1.f / 64.f));
}

// ---- W reorder: [o][c][kh][kw] f32 -> [k9][o][c] bf16 ----
__global__ __launch_bounds__(256) void prep_w(const float* __restrict__ W,
                                              unsigned short* __restrict__ Wr) {
    int id = blockIdx.x * 256 + threadIdx.x;
    if (id >= 9 * 128 * 64) return;
    int c = id & 63, o = (id >> 6) & 127, k9 = id >> 13;
    Wr[id] = f2bf(W[(o * 64 + c) * 9 + k9]);
}

// ---- main conv: block=(n,f,t-half), 4 waves, out 128o x 128t,
//      K pipelined as 6 steps of (kh, 32c) with ping-pong LDS ----
__global__ __launch_bounds__(256) void damp_conv_mfma(
    const float* __restrict__ x, const unsigned short* __restrict__ Wr,
    const float* __restrict__ b, float* __restrict__ out)
{
    __shared__ unsigned short xs[2][TL * CP];  // 18,720 B total

    const int tid  = threadIdx.x;
    const int lane = tid & 63;
    const int wid  = tid >> 6;       // 0..3
    const int q    = lane & 3;
    const int p16  = lane >> 2;

    const int raw = blockIdx.x;
    const int logical = (raw & 7) * 1024 + (raw >> 3);  // XCD-chunked, bijective
    const int n  = logical >> 8;
    const int f  = (logical >> 1) & 127;
    const int th = logical & 1;
    const int tbase = th * 128;

    const int lo16 = lane & 15;
    const int hi2  = lane >> 4;
    const int m0 = (wid >> 1) * 64;  // wave o-base
    const int n0 = (wid & 1) * 64;   // wave t-base (local)

    const unsigned selv = (q & 1) ? 0x07060302u : 0x05040100u;

    float dmp[2][4];
    #pragma unroll
    for (int s = 0; s < 2; ++s)
        #pragma unroll
        for (int j = 0; j < 4; ++j)
            dmp[s][j] = dampf((float)(tbase + 64 * s + 4 * p16 + j));

    f32x4 acc[4][4];
    #pragma unroll
    for (int i = 0; i < 4; ++i)
        #pragma unroll
        for (int j = 0; j < 4; ++j) acc[i][j] = (f32x4){0.f, 0.f, 0.f, 0.f};

    float4 rb[4];   // single reg staging buffer (issue(i+1) always follows write(i))
    float  hv;

    // step it = (kh, cc): stage 1 f-row x 32 c x 128 t  (4 float4/thread)
    auto issue_i = [&](int it) {
        int kh = it >> 1, cc = (it & 1) * 32;
        int fg = f + kh - 1;
        bool fok = (unsigned)fg < 128u;
        #pragma unroll
        for (int j = 0; j < 4; ++j) {
            int idx = wid * 4 + j;            // 0..15
            int c0 = (idx >> 1) * 4;
            int s  = j & 1;                    // (wid*4+j)&1 == j&1
            const float* src = x + (((size_t)(n * 64 + cc + c0 + q)) * 128 + (fok ? fg : 0)) * 256
                             + tbase + 64 * s + 4 * p16;
            rb[j] = fok ? *(const float4*)src : (float4){0.f, 0.f, 0.f, 0.f};
        }
        hv = 0.f;
        if (tid < 32) {            // interior halo column (real t neighbor)
            int c = tid;
            if (fok) hv = x[(((size_t)(n * 64 + cc + c)) * 128 + fg) * 256 + (th ? 127 : 128)];
        }
    };

    auto write_i = [&](int bsel) {
        #pragma unroll
        for (int j = 0; j < 4; ++j) {
            int idx = wid * 4 + j;
            int c0 = (idx >> 1) * 4;
            const int s = j & 1;
            float4 v = rb[j];
            unsigned d0 = (unsigned)f2bf(v.x * dmp[s][0]) | ((unsigned)f2bf(v.y * dmp[s][1]) << 16);
            unsigned d1 = (unsigned)f2bf(v.z * dmp[s][2]) | ((unsigned)f2bf(v.w * dmp[s][3]) << 16);
            // 4x4 u16 quad transpose -> lane owns 4 consecutive c at t_loc = 64s + lane
            unsigned p0 = __shfl_xor((int)d0, 2);
            unsigned p1 = __shfl_xor((int)d1, 2);
            bool hi = (lane >> 1) & 1;
            unsigned own = hi ? d1 : d0;
            unsigned oth = hi ? p1 : p0;
            unsigned sown = __shfl_xor((int)own, 1);
            unsigned soth = __shfl_xor((int)oth, 1);
            bool b0 = q & 1, b1 = q & 2;
            unsigned a0 = b0 ? sown : own, a1 = b0 ? own : sown;
            unsigned g0 = b0 ? soth : oth, g1 = b0 ? oth : soth;
            unsigned e0 = b1 ? g0 : a0, e1 = b1 ? g1 : a1;
            unsigned e2 = b1 ? a0 : g0, e3 = b1 ? a1 : g1;
            unsigned r0 = __builtin_amdgcn_perm(e1, e0, selv);
            unsigned r1 = __builtin_amdgcn_perm(e3, e2, selv);
            unsigned* dst = (unsigned*)&xs[bsel][(1 + 64 * s + lane) * CP + c0];
            dst[0] = r0;
            dst[1] = r1;
        }
        if (tid < 32) {
            int c = tid;
            float dh = dampf(th ? 127.f : 128.f);
            xs[bsel][(th ? 0 : TL - 1) * CP + c] = f2bf(hv * dh);   // real side
            xs[bsel][(th ? TL - 1 : 0) * CP + c] = 0;               // pad side
        }
    };

    auto mfma_i = [&](int it, int bsel) {
        int kh = it >> 1, cc = (it & 1) * 32;
        #pragma unroll
        for (int kw = 0; kw < 3; ++kw) {
            bf16x8 af[4];
            #pragma unroll
            for (int fm = 0; fm < 4; ++fm) {
                int o = m0 + fm * 16 + lo16;
                af[fm] = *(const bf16x8*)(Wr + (((kh * 3 + kw) * 128 + o) * 64 + cc + hi2 * 8));
            }
            #pragma unroll
            for (int fn = 0; fn < 4; ++fn) {
                int row = n0 + fn * 16 + lo16 + kw;
                const unsigned short* pb = &xs[bsel][row * CP + hi2 * 8];
                short4v blo = *(const short4v*)pb;
                short4v bhi = *(const short4v*)(pb + 4);
                bf16x8 bx = {blo.x, blo.y, blo.z, blo.w, bhi.x, bhi.y, bhi.z, bhi.w};
                __builtin_amdgcn_s_setprio(1);
                #pragma unroll
                for (int fm = 0; fm < 4; ++fm)
                    acc[fm][fn] = __builtin_amdgcn_mfma_f32_16x16x32_bf16(
                        af[fm], bx, acc[fm][fn], 0, 0, 0);
                __builtin_amdgcn_s_setprio(0);
            }
        }
    };

    issue_i(0);
    write_i(0);
    __syncthreads();

    #pragma unroll
    for (int i = 0; i < 6; ++i) {
        if (i < 5) issue_i(i + 1);       // loads in flight under this step's MFMAs
        mfma_i(i, i & 1);
        __syncthreads();                 // all waves done reading xs[i&1] (and earlier (i+1)&1)
        if (i < 5) {
            write_i((i + 1) & 1);        // fill the buffer freed at step i-1
            __syncthreads();
        }
    }

    // ---- epilogue ----
    #pragma unroll
    for (int fm = 0; fm < 4; ++fm) {
        int obase = m0 + fm * 16 + hi2 * 4;
        #pragma unroll
        for (int r = 0; r < 4; ++r) {
            int o = obase + r;
            float bias = b[o];
            #pragma unroll
            for (int fn = 0; fn < 4; ++fn) {
                int t = tbase + n0 + fn * 16 + lo16;
                out[(((size_t)n * 128 + o) * 128 + f) * 256 + t] = acc[fm][fn][r] + bias;
            }
        }
    }
}

extern "C" void kernel_launch(void* const* d_in, const int* in_sizes, int n_in,
                              void* d_out, int out_size, void* d_ws, size_t ws_size,
                              hipStream_t stream) {
    const float* x = (const float*)d_in[0];
    const float* W = (const float*)d_in[1];
    const float* b = (const float*)d_in[2];
    float* out = (float*)d_out;
    unsigned short* Wr = (unsigned short*)d_ws;  // 147,456 B

    hipLaunchKernelGGL(prep_w, dim3(288), dim3(256), 0, stream, W, Wr);
    hipLaunchKernelGGL(damp_conv_mfma, dim3(8192), dim3(256), 0, stream, x, Wr, b, out);
}